// Round 10
// baseline (385.348 us; speedup 1.0000x reference)
//
#include <hip/hip_runtime.h>
#include <stdint.h>

#define Bdim 16
#define Sdim 4096
#define Hdim 512
#define Mdim (Bdim*Sdim)      // 65536
#define N3   (3*Hdim)         // 1536
#define Kdim 512
#define NCHUNK 64
#define CLEN  (Sdim/NCHUNK)   // 64

typedef __bf16 bf16;
typedef __bf16 bf16x4 __attribute__((ext_vector_type(4)));
typedef __bf16 bf16x8 __attribute__((ext_vector_type(8)));
typedef float  f32x4  __attribute__((ext_vector_type(4)));
typedef _Float16 f16;
typedef _Float16 f16x4 __attribute__((ext_vector_type(4)));
typedef _Float16 f16x8 __attribute__((ext_vector_type(8)));

__device__ __forceinline__ void gload_lds16(const void* g, void* l) {
  __builtin_amdgcn_global_load_lds(
      (const __attribute__((address_space(1))) uint32_t*)g,
      (__attribute__((address_space(3))) uint32_t*)l, 16, 0, 0);
}

// ---------- fp32 -> bf16 convert (for W only; A is fused into GEMM) ----------
__global__ void __launch_bounds__(256) cvt_kernel(const float4* __restrict__ in,
                                                  bf16x4* __restrict__ out, int n4) {
  int i = blockIdx.x * blockDim.x + threadIdx.x;
  if (i >= n4) return;
  float4 v = in[i];
  bf16x4 o;
  o.x = (bf16)v.x; o.y = (bf16)v.y; o.z = (bf16)v.z; o.w = (bf16)v.w;
  out[i] = o;
}

// ====== 256x256 MFMA GEMM, fp32-A staging (fused convert), BK=32 ======
// A: (M,K) fp32 row-major (staged raw, converted to bf16 after ds_read);
// Wb: (N,K) bf16 row-major. C = A*Wb^T, fused bias+activation -> f16 gates.
// Simple 2-phase loop: stage(t+1) -> ds_read(t) -> cvt -> MFMA -> syncthreads.
// LDS 96KB: A bufs fp32 2x32KB @0/@32768; B bufs bf16 2x16KB @65536/@81920.
// A swizzle: 8x16B slots/row, s' = s ^ (row&7).  B swizzle: 4 slots, s^((row>>1)&3).
#define BM 256
#define BN 256
#define BK2 32
#define NT (Kdim/BK2)   // 16

__global__ void __launch_bounds__(512, 2) gemm_act_kernel(
    const float* __restrict__ A, const bf16* __restrict__ Wb,
    const float* __restrict__ bias,
    f16* __restrict__ zbuf, f16* __restrict__ fbuf, f16* __restrict__ ogbuf) {
  __shared__ char lds[98304];
  const int tid  = threadIdx.x;
  const int wid  = tid >> 6;
  const int lane = tid & 63;
  const int wr = wid >> 2, wc = wid & 3;   // 2(M) x 4(N) waves; wave tile 128x64
  // XCD-chunked bijective swizzle: 1536 blocks = 8 XCDs x 192
  const int bid = blockIdx.x;
  const int wg  = (bid & 7) * 192 + (bid >> 3);
  const int mt = wg / (N3 / BN);
  const int nt = wg % (N3 / BN);           // 6 N-tiles, inner -> A reuse per XCD
  const int row0 = mt * BM;

  const float* Ag = A  + (size_t)row0 * Kdim;
  const bf16*  Bg = Wb + (size_t)(nt * BN) * Kdim;

  // A staging: per K-step 256 rows x 8 slots x 16B = 32KB = 2048 chunks;
  // thread covers c = i*512+tid, i=0..3. Source slot pre-swizzled ^ (row&7).
  uint32_t srcA[4];
  #pragma unroll
  for (int i = 0; i < 4; ++i) {
    int c = i * 512 + tid;
    int row = c >> 3, slot = c & 7;
    srcA[i] = (uint32_t)(row * Kdim + ((slot ^ (row & 7)) << 2));  // fp32 elems
  }
  // B staging: per K-step 256 rows x 4 slots x 16B = 16KB = 1024 chunks; i=0..1.
  uint32_t srcB[2];
  #pragma unroll
  for (int i = 0; i < 2; ++i) {
    int c = i * 512 + tid;
    int row = c >> 2, slot = c & 3;
    srcB[i] = (uint32_t)(row * Kdim + ((slot ^ ((row >> 1) & 3)) << 3));  // bf16 elems
  }
  const uint32_t dstBase = (uint32_t)(wid * 1024);  // bytes, wave-uniform

  // ds_read offsets. A: row stride 128B; lane's k-window = kslot*8 fp32 ->
  // slots s0=2*kslot (k0-3), s0^... second half differs by ^16 bytes.
  const int kslot = lane >> 4;
  uint32_t byteA[8], byteB[4];
  #pragma unroll
  for (int m = 0; m < 8; ++m) {
    int row = wr * 128 + m * 16 + (lane & 15);
    byteA[m] = (uint32_t)(row * 128 + (((2 * kslot) ^ (row & 7)) << 4));
  }
  #pragma unroll
  for (int n = 0; n < 4; ++n) {
    int row = wc * 64 + n * 16 + (lane & 15);
    byteB[n] = (uint32_t)(row * 64 + ((kslot ^ ((row >> 1) & 3)) << 4));
  }

  f32x4 acc[8][4];
  #pragma unroll
  for (int m = 0; m < 8; ++m)
    #pragma unroll
    for (int n = 0; n < 4; ++n)
      acc[m][n] = (f32x4){0.f, 0.f, 0.f, 0.f};

  // prologue: stage tile 0
  {
    char* Ad = lds; char* Bd = lds + 65536;
    #pragma unroll
    for (int i = 0; i < 4; ++i) gload_lds16(Ag + srcA[i], Ad + i * 8192 + dstBase);
    #pragma unroll
    for (int i = 0; i < 2; ++i) gload_lds16(Bg + srcB[i], Bd + i * 8192 + dstBase);
  }
  __syncthreads();

  for (int t = 0; t < NT; ++t) {
    if (t + 1 < NT) {  // stage next tile into other buffers
      char* Ad = lds + ((t + 1) & 1) * 32768;
      char* Bd = lds + 65536 + ((t + 1) & 1) * 16384;
      #pragma unroll
      for (int i = 0; i < 4; ++i)
        gload_lds16(Ag + srcA[i] + (t + 1) * BK2, Ad + i * 8192 + dstBase);
      #pragma unroll
      for (int i = 0; i < 2; ++i)
        gload_lds16(Bg + srcB[i] + (t + 1) * BK2, Bd + i * 8192 + dstBase);
    }
    const char* Ab = lds + (t & 1) * 32768;
    const char* Bb = lds + 65536 + (t & 1) * 16384;
    bf16x8 af[8], bfrag[4];
    #pragma unroll
    for (int m = 0; m < 8; ++m) {
      float4 x = *(const float4*)(Ab + byteA[m]);
      float4 y = *(const float4*)(Ab + (byteA[m] ^ 16u));
      bf16x8 fr;
      fr[0] = (bf16)x.x; fr[1] = (bf16)x.y; fr[2] = (bf16)x.z; fr[3] = (bf16)x.w;
      fr[4] = (bf16)y.x; fr[5] = (bf16)y.y; fr[6] = (bf16)y.z; fr[7] = (bf16)y.w;
      af[m] = fr;
    }
    #pragma unroll
    for (int n = 0; n < 4; ++n) bfrag[n] = *(const bf16x8*)(Bb + byteB[n]);
    __builtin_amdgcn_s_setprio(1);
    #pragma unroll
    for (int m = 0; m < 8; ++m)
      #pragma unroll
      for (int n = 0; n < 4; ++n)
        acc[m][n] = __builtin_amdgcn_mfma_f32_16x16x32_bf16(af[m], bfrag[n], acc[m][n], 0, 0, 0);
    __builtin_amdgcn_s_setprio(0);
    __syncthreads();
  }

  // ---- epilogue: activation, repack via LDS (first 64KB), coalesced stores ----
  const int gate = nt >> 1;                 // BN=256 divides each 512-col gate
  const int cbn  = (nt & 1) * 256;
  f16* dst = (gate == 0) ? zbuf : ((gate == 1) ? fbuf : ogbuf);
  float bv[4];
  #pragma unroll
  for (int n = 0; n < 4; ++n)
    bv[n] = bias[gate * Hdim + cbn + wc * 64 + n * 16 + (lane & 15)];

  #pragma unroll
  for (int R = 0; R < 2; ++R) {
    #pragma unroll
    for (int m4 = 0; m4 < 4; ++m4) {
      const int m = R * 4 + m4;
      #pragma unroll
      for (int n = 0; n < 4; ++n) {
        int col = wc * 64 + n * 16 + (lane & 15);
        #pragma unroll
        for (int r = 0; r < 4; ++r) {
          int Lrow = wr * 64 + m4 * 16 + (lane >> 4) * 4 + r;
          float y = acc[m][n][r] + bv[n];
          float v;
          if (gate == 0) {                       // tanh(y) = 1 - 2/(e^{2y}+1)
            float e = __expf(2.f * y);
            v = 1.f - 2.f / (e + 1.f);
          } else {                               // sigmoid
            v = 1.f / (1.f + __expf(-y));
          }
          uint32_t byte = (uint32_t)(Lrow * 512 + col * 2) ^ ((uint32_t)(Lrow & 7) << 4);
          *(f16*)(lds + byte) = (f16)v;
        }
      }
    }
    __syncthreads();
    #pragma unroll
    for (int j = 0; j < 8; ++j) {
      int c = j * 512 + tid;
      int Lrow = c >> 5, col8 = c & 31;
      uint32_t byte = (uint32_t)(Lrow * 512 + col8 * 16) ^ ((uint32_t)(Lrow & 7) << 4);
      f16x8 v = *(const f16x8*)(lds + byte);
      int G = (Lrow >> 6) * 128 + R * 64 + (Lrow & 63);
      *(f16x8*)&dst[(size_t)(row0 + G) * Hdim + cbn + col8 * 8] = v;
    }
    __syncthreads();
  }
}

// ---------- scan pass A: per-chunk composite (P = prod(1-f), Q = local scan) ----------
__global__ void __launch_bounds__(256) scanA_kernel(const f16x4* __restrict__ z4,
                                                    const f16x4* __restrict__ f4,
                                                    float* __restrict__ Pb,
                                                    float* __restrict__ Qb) {
  int u  = blockIdx.x * blockDim.x + threadIdx.x;  // 131072 = NCHUNK*B*128
  int hq = u & 127;
  int bc = u >> 7;
  int b  = bc & (Bdim - 1);
  int c  = bc >> 4;
  size_t base = ((size_t)(b * Sdim + c * CLEN)) * 128 + hq;  // in quads
  float P[4] = {1.f, 1.f, 1.f, 1.f}, Q[4] = {0.f, 0.f, 0.f, 0.f};
  #pragma unroll 4
  for (int s = 0; s < CLEN; ++s) {
    f16x4 fv = f4[base], zv = z4[base];
    #pragma unroll
    for (int j = 0; j < 4; ++j) {
      float f = (float)fv[j];
      Q[j] += f * ((float)zv[j] - Q[j]);
      P[j] *= (1.f - f);
    }
    base += 128;
  }
  int outi = ((c * Bdim + b) << 9) + hq * 4;
  *(float4*)&Pb[outi] = make_float4(P[0], P[1], P[2], P[3]);
  *(float4*)&Qb[outi] = make_float4(Q[0], Q[1], Q[2], Q[3]);
}

// ---------- scan pass B: scan chunk composites -> h_in per chunk + c_last ----------
__global__ void __launch_bounds__(256) scanB_kernel(const float* __restrict__ Pb,
                                                    const float* __restrict__ Qb,
                                                    float* __restrict__ hin,
                                                    float* __restrict__ c_last) {
  int t = blockIdx.x * blockDim.x + threadIdx.x;  // 8192 = B*H
  int h = t & (Hdim - 1), b = t >> 9;
  float hs = 0.f;
  #pragma unroll 8
  for (int c = 0; c < NCHUNK; ++c) {
    hin[c * (Bdim * Hdim) + t] = hs;
    int u = ((c * Bdim + b) << 9) + h;
    hs = Pb[u] * hs + Qb[u];
  }
  c_last[t] = hs;
}

// ---------- scan pass C: rerun chunk with correct h_in, fuse out = og * h ----------
__global__ void __launch_bounds__(256) scanC_kernel(const f16x4* __restrict__ z4,
                                                    const f16x4* __restrict__ f4,
                                                    const f16x4* __restrict__ og4,
                                                    const float* __restrict__ hin,
                                                    float4* __restrict__ out4) {
  int u  = blockIdx.x * blockDim.x + threadIdx.x;
  int hq = u & 127;
  int bc = u >> 7;
  int b  = bc & (Bdim - 1);
  int c  = bc >> 4;
  float4 hv = *(const float4*)&hin[c * (Bdim * Hdim) + b * Hdim + hq * 4];
  float h[4] = {hv.x, hv.y, hv.z, hv.w};
  size_t base = ((size_t)(b * Sdim + c * CLEN)) * 128 + hq;
  #pragma unroll 4
  for (int s = 0; s < CLEN; ++s) {
    f16x4 fv = f4[base], zv = z4[base], ov = og4[base];
    float4 o;
    #pragma unroll
    for (int j = 0; j < 4; ++j) {
      h[j] += (float)fv[j] * ((float)zv[j] - h[j]);
    }
    o.x = (float)ov[0] * h[0]; o.y = (float)ov[1] * h[1];
    o.z = (float)ov[2] * h[2]; o.w = (float)ov[3] * h[3];
    out4[base] = o;
    base += 128;
  }
}

extern "C" void kernel_launch(void* const* d_in, const int* in_sizes, int n_in,
                              void* d_out, int out_size, void* d_ws, size_t ws_size,
                              hipStream_t stream) {
  const float* inp  = (const float*)d_in[0];
  const float* W    = (const float*)d_in[1];
  const float* bias = (const float*)d_in[2];
  float* out = (float*)d_out;

  char* ws = (char*)d_ws;
  // workspace layout (bytes), total ~276 MB (Abf region now unused)
  bf16* Wbf = (bf16*)(ws + 67108864);        //   1,572,864
  f16*  zh  = (f16*) (ws + 68681728);        //  67,108,864
  f16*  fh  = (f16*) (ws + 135790592);       //  67,108,864
  f16*  ogh = (f16*) (ws + 202899456);       //  67,108,864
  float* Pb = (float*)(ws + 270008320);      //   2,097,152
  float* Qb = (float*)(ws + 272105472);      //   2,097,152
  float* hin= (float*)(ws + 274202624);      //   2,097,152

  // 1) convert W to bf16 (A is consumed as fp32 directly by the GEMM)
  {
    int n4 = (N3 * Kdim) / 4;    // 196,608
    cvt_kernel<<<n4 / 256, 256, 0, stream>>>((const float4*)W, (bf16x4*)Wbf, n4);
  }
  // 2) GEMM (fp32-A fused convert) + bias + activations -> fp16 gates
  gemm_act_kernel<<<(Mdim / BM) * (N3 / BN), 512, 0, stream>>>(inp, Wbf, bias,
                                                               zh, fh, ogh);
  // 3) chunked linear-recurrence scan
  scanA_kernel<<<(NCHUNK * Bdim * 128) / 256, 256, 0, stream>>>(
      (const f16x4*)zh, (const f16x4*)fh, Pb, Qb);
  scanB_kernel<<<(Bdim * Hdim) / 256, 256, 0, stream>>>(Pb, Qb, hin,
                                                        out + (size_t)Mdim * Hdim);
  scanC_kernel<<<(NCHUNK * Bdim * 128) / 256, 256, 0, stream>>>(
      (const f16x4*)zh, (const f16x4*)fh, (const f16x4*)ogh, hin, (float4*)out);
}

// Round 11
// 379.649 us; speedup vs baseline: 1.0150x; 1.0150x over previous
//
#include <hip/hip_runtime.h>
#include <stdint.h>

#define Bdim 16
#define Sdim 4096
#define Hdim 512
#define Mdim (Bdim*Sdim)      // 65536
#define N3   (3*Hdim)         // 1536
#define Kdim 512
#define NCHUNK 64
#define CLEN  (Sdim/NCHUNK)   // 64

typedef __bf16 bf16;
typedef __bf16 bf16x4 __attribute__((ext_vector_type(4)));
typedef __bf16 bf16x8 __attribute__((ext_vector_type(8)));
typedef float  f32x4  __attribute__((ext_vector_type(4)));
typedef _Float16 f16;
typedef _Float16 f16x4 __attribute__((ext_vector_type(4)));
typedef _Float16 f16x8 __attribute__((ext_vector_type(8)));

// ---------- fp32 -> bf16 convert (W only; A convert is fused into GEMM) ----------
__global__ void __launch_bounds__(256) cvt_kernel(const float4* __restrict__ in,
                                                  bf16x4* __restrict__ out, int n4) {
  int i = blockIdx.x * blockDim.x + threadIdx.x;
  if (i >= n4) return;
  float4 v = in[i];
  bf16x4 o;
  o.x = (bf16)v.x; o.y = (bf16)v.y; o.z = (bf16)v.z; o.w = (bf16)v.w;
  out[i] = o;
}

// ====== 256x256 MFMA GEMM, REG-STAGED operands (T14), fused A-convert ======
// A: (M,K) fp32 row-major (global->reg->cvt->ds_write, 1-step pipeline);
// Wb: (N,K) bf16 row-major (global->reg->ds_write). C = A*Wb^T + bias, act.
// No global_load_lds anywhere -> barriers drain lgkm only; the in-flight
// register loads (issued one full step early) cross barriers freely, hiding
// HBM/L2 latency under the step's MFMA. LDS 64KB: buf p at p*32768
// (A bf16 16KB + B bf16 16KB); same swizzle & epilogue as round 9 (verified).
#define BM 256
#define BN 256
#define BK2 32
#define NT (Kdim/BK2)   // 16

__global__ void __launch_bounds__(512, 2) gemm_act_kernel(
    const float* __restrict__ A, const bf16* __restrict__ Wb,
    const float* __restrict__ bias,
    f16* __restrict__ zbuf, f16* __restrict__ fbuf, f16* __restrict__ ogbuf) {
  __shared__ char lds[65536];
  const int tid  = threadIdx.x;
  const int wid  = tid >> 6;
  const int lane = tid & 63;
  const int wr = wid >> 2, wc = wid & 3;   // 2(M) x 4(N) waves; wave tile 128x64
  // XCD-chunked bijective swizzle: 1536 blocks = 8 XCDs x 192
  const int bid = blockIdx.x;
  const int wg  = (bid & 7) * 192 + (bid >> 3);
  const int mt = wg / (N3 / BN);
  const int nt = wg % (N3 / BN);           // 6 N-tiles, inner -> A reuse per XCD
  const int row0 = mt * BM;

  const float* Ag = A  + (size_t)row0 * Kdim;
  const bf16*  Bg = Wb + (size_t)(nt * BN) * Kdim;

  // staging: per tile each operand = 256 rows x 4 x 16B-slots (bf16) = 16KB.
  // thread covers chunk c = i*512 + tid (i=0,1): row = i*128 + (tid>>2),
  // slot = tid&3. Source pre-swizzled: slot ^ ((row>>1)&3); LDS dest linear.
  uint32_t src[2];
  {
    int r_ = tid >> 2, slot = tid & 3;
    #pragma unroll
    for (int i = 0; i < 2; ++i) {
      int row = i * 128 + r_;
      src[i] = (uint32_t)(row * Kdim + ((slot ^ ((row >> 1) & 3)) << 3));  // elements
    }
  }
  const uint32_t dstB = (uint32_t)(tid * 16);  // + i*8192, bytes within operand

  // ds_read byte offsets within a 32KB buffer; row stride 64B, kslot = lane>>4
  uint32_t byteA[8], byteB[4];
  {
    int kslot = lane >> 4;
    #pragma unroll
    for (int m = 0; m < 8; ++m) {
      int row = wr * 128 + m * 16 + (lane & 15);
      byteA[m] = (uint32_t)(row * 64 + ((kslot ^ ((row >> 1) & 3)) << 4));
    }
    #pragma unroll
    for (int n = 0; n < 4; ++n) {
      int row = wc * 64 + n * 16 + (lane & 15);
      byteB[n] = (uint32_t)(16384 + row * 64 + ((kslot ^ ((row >> 1) & 3)) << 4));
    }
  }

  f32x4 acc[8][4];
  #pragma unroll
  for (int m = 0; m < 8; ++m)
    #pragma unroll
    for (int n = 0; n < 4; ++n)
      acc[m][n] = (f32x4){0.f, 0.f, 0.f, 0.f};

  float4 arg[2][2];   // A tile in flight: [chunk][half], fp32
  float4 brg[2];      // B tile in flight: [chunk], 16B bf16 payload

  // LOAD tile t into regs (issue only; no waits here)
  #define LOADT(t_) do {                                                     \
    const float* Ap = Ag + (t_) * BK2;                                       \
    const bf16*  Bp = Bg + (t_) * BK2;                                       \
    _Pragma("unroll")                                                        \
    for (int i = 0; i < 2; ++i) {                                            \
      arg[i][0] = *(const float4*)(Ap + src[i]);                             \
      arg[i][1] = *(const float4*)(Ap + src[i] + 4);                         \
      brg[i]    = *(const float4*)(const void*)(Bp + src[i]);                \
    }                                                                        \
  } while (0)

  // WRITE regs (tile t) into LDS buf (t&1): cvt A fp32->bf16, B passthrough
  #define WRITET(t_) do {                                                    \
    char* Ad = lds + ((t_) & 1) * 32768;                                     \
    char* Bd = Ad + 16384;                                                   \
    _Pragma("unroll")                                                        \
    for (int i = 0; i < 2; ++i) {                                            \
      bf16x8 fr;                                                             \
      fr[0] = (bf16)arg[i][0].x; fr[1] = (bf16)arg[i][0].y;                  \
      fr[2] = (bf16)arg[i][0].z; fr[3] = (bf16)arg[i][0].w;                  \
      fr[4] = (bf16)arg[i][1].x; fr[5] = (bf16)arg[i][1].y;                  \
      fr[6] = (bf16)arg[i][1].z; fr[7] = (bf16)arg[i][1].w;                  \
      *(bf16x8*)(Ad + i * 8192 + dstB) = fr;                                 \
      *(float4*)(Bd + i * 8192 + dstB) = brg[i];                             \
    }                                                                        \
  } while (0)

  // prologue: tile 0 load -> write -> issue tile 1 loads
  LOADT(0);
  WRITET(0);          // compiler vmcnt-waits tile-0 loads here (once)
  LOADT(1);
  __syncthreads();    // lgkm drain; tile-1 reg loads stay in flight

  #pragma unroll 2
  for (int t = 0; t < NT; ++t) {
    if (t + 1 < NT) WRITET(t + 1);   // regs loaded last step -> already landed
    if (t + 2 < NT) LOADT(t + 2);    // issue; lands during next step
    const char* Ab = lds + (t & 1) * 32768;
    bf16x8 af[8], bfrag[4];
    #pragma unroll
    for (int m = 0; m < 8; ++m) af[m] = *(const bf16x8*)(Ab + byteA[m]);
    #pragma unroll
    for (int n = 0; n < 4; ++n) bfrag[n] = *(const bf16x8*)(Ab + byteB[n]);
    #pragma unroll
    for (int m = 0; m < 8; ++m)
      #pragma unroll
      for (int n = 0; n < 4; ++n)
        acc[m][n] = __builtin_amdgcn_mfma_f32_16x16x32_bf16(af[m], bfrag[n], acc[m][n], 0, 0, 0);
    __syncthreads();  // lgkm-only drain (no DMA/global stores pending)
  }

  // ---- epilogue: activation, repack via full 64KB LDS, coalesced stores ----
  const int gate = nt >> 1;                 // BN=256 divides each 512-col gate
  const int cbn  = (nt & 1) * 256;
  f16* dst = (gate == 0) ? zbuf : ((gate == 1) ? fbuf : ogbuf);
  float bv[4];
  #pragma unroll
  for (int n = 0; n < 4; ++n)
    bv[n] = bias[gate * Hdim + cbn + wc * 64 + n * 16 + (lane & 15)];

  #pragma unroll
  for (int R = 0; R < 2; ++R) {
    #pragma unroll
    for (int m4 = 0; m4 < 4; ++m4) {
      const int m = R * 4 + m4;
      #pragma unroll
      for (int n = 0; n < 4; ++n) {
        int col = wc * 64 + n * 16 + (lane & 15);
        #pragma unroll
        for (int r = 0; r < 4; ++r) {
          int Lrow = wr * 64 + m4 * 16 + (lane >> 4) * 4 + r;
          float y = acc[m][n][r] + bv[n];
          float v;
          if (gate == 0) {                       // tanh(y) = 1 - 2/(e^{2y}+1)
            float e = __expf(2.f * y);
            v = 1.f - 2.f / (e + 1.f);
          } else {                               // sigmoid
            v = 1.f / (1.f + __expf(-y));
          }
          uint32_t byte = (uint32_t)(Lrow * 512 + col * 2) ^ ((uint32_t)(Lrow & 7) << 4);
          *(f16*)(lds + byte) = (f16)v;
        }
      }
    }
    __syncthreads();
    #pragma unroll
    for (int j = 0; j < 8; ++j) {
      int c = j * 512 + tid;
      int Lrow = c >> 5, col8 = c & 31;
      uint32_t byte = (uint32_t)(Lrow * 512 + col8 * 16) ^ ((uint32_t)(Lrow & 7) << 4);
      f16x8 v = *(const f16x8*)(lds + byte);
      int G = (Lrow >> 6) * 128 + R * 64 + (Lrow & 63);
      *(f16x8*)&dst[(size_t)(row0 + G) * Hdim + cbn + col8 * 8] = v;
    }
    __syncthreads();
  }
}

// ---------- scan pass A: per-chunk composite (P = prod(1-f), Q = local scan) ----------
__global__ void __launch_bounds__(256) scanA_kernel(const f16x4* __restrict__ z4,
                                                    const f16x4* __restrict__ f4,
                                                    float* __restrict__ Pb,
                                                    float* __restrict__ Qb) {
  int u  = blockIdx.x * blockDim.x + threadIdx.x;  // 131072 = NCHUNK*B*128
  int hq = u & 127;
  int bc = u >> 7;
  int b  = bc & (Bdim - 1);
  int c  = bc >> 4;
  size_t base = ((size_t)(b * Sdim + c * CLEN)) * 128 + hq;  // in quads
  float P[4] = {1.f, 1.f, 1.f, 1.f}, Q[4] = {0.f, 0.f, 0.f, 0.f};
  #pragma unroll 4
  for (int s = 0; s < CLEN; ++s) {
    f16x4 fv = f4[base], zv = z4[base];
    #pragma unroll
    for (int j = 0; j < 4; ++j) {
      float f = (float)fv[j];
      Q[j] += f * ((float)zv[j] - Q[j]);
      P[j] *= (1.f - f);
    }
    base += 128;
  }
  int outi = ((c * Bdim + b) << 9) + hq * 4;
  *(float4*)&Pb[outi] = make_float4(P[0], P[1], P[2], P[3]);
  *(float4*)&Qb[outi] = make_float4(Q[0], Q[1], Q[2], Q[3]);
}

// ---------- scan pass B: scan chunk composites -> h_in per chunk + c_last ----------
__global__ void __launch_bounds__(256) scanB_kernel(const float* __restrict__ Pb,
                                                    const float* __restrict__ Qb,
                                                    float* __restrict__ hin,
                                                    float* __restrict__ c_last) {
  int t = blockIdx.x * blockDim.x + threadIdx.x;  // 8192 = B*H
  int h = t & (Hdim - 1), b = t >> 9;
  float hs = 0.f;
  #pragma unroll 8
  for (int c = 0; c < NCHUNK; ++c) {
    hin[c * (Bdim * Hdim) + t] = hs;
    int u = ((c * Bdim + b) << 9) + h;
    hs = Pb[u] * hs + Qb[u];
  }
  c_last[t] = hs;
}

// ---------- scan pass C: rerun chunk with correct h_in, fuse out = og * h ----------
__global__ void __launch_bounds__(256) scanC_kernel(const f16x4* __restrict__ z4,
                                                    const f16x4* __restrict__ f4,
                                                    const f16x4* __restrict__ og4,
                                                    const float* __restrict__ hin,
                                                    float4* __restrict__ out4) {
  int u  = blockIdx.x * blockDim.x + threadIdx.x;
  int hq = u & 127;
  int bc = u >> 7;
  int b  = bc & (Bdim - 1);
  int c  = bc >> 4;
  float4 hv = *(const float4*)&hin[c * (Bdim * Hdim) + b * Hdim + hq * 4];
  float h[4] = {hv.x, hv.y, hv.z, hv.w};
  size_t base = ((size_t)(b * Sdim + c * CLEN)) * 128 + hq;
  #pragma unroll 4
  for (int s = 0; s < CLEN; ++s) {
    f16x4 fv = f4[base], zv = z4[base], ov = og4[base];
    float4 o;
    #pragma unroll
    for (int j = 0; j < 4; ++j) {
      h[j] += (float)fv[j] * ((float)zv[j] - h[j]);
    }
    o.x = (float)ov[0] * h[0]; o.y = (float)ov[1] * h[1];
    o.z = (float)ov[2] * h[2]; o.w = (float)ov[3] * h[3];
    out4[base] = o;
    base += 128;
  }
}

extern "C" void kernel_launch(void* const* d_in, const int* in_sizes, int n_in,
                              void* d_out, int out_size, void* d_ws, size_t ws_size,
                              hipStream_t stream) {
  const float* inp  = (const float*)d_in[0];
  const float* W    = (const float*)d_in[1];
  const float* bias = (const float*)d_in[2];
  float* out = (float*)d_out;

  char* ws = (char*)d_ws;
  // workspace layout (bytes), total ~276 MB
  bf16* Wbf = (bf16*)(ws + 67108864);        //   1,572,864
  f16*  zh  = (f16*) (ws + 68681728);        //  67,108,864
  f16*  fh  = (f16*) (ws + 135790592);       //  67,108,864
  f16*  ogh = (f16*) (ws + 202899456);       //  67,108,864
  float* Pb = (float*)(ws + 270008320);      //   2,097,152
  float* Qb = (float*)(ws + 272105472);      //   2,097,152
  float* hin= (float*)(ws + 274202624);      //   2,097,152

  // 1) convert W to bf16 (A is consumed fp32 by the GEMM, converted in-reg)
  {
    int n4 = (N3 * Kdim) / 4;    // 196,608
    cvt_kernel<<<n4 / 256, 256, 0, stream>>>((const float4*)W, (bf16x4*)Wbf, n4);
  }
  // 2) GEMM (reg-staged, fused A-convert) + bias + activations -> fp16 gates
  gemm_act_kernel<<<(Mdim / BM) * (N3 / BN), 512, 0, stream>>>(inp, Wbf, bias,
                                                               zh, fh, ogh);
  // 3) chunked linear-recurrence scan
  scanA_kernel<<<(NCHUNK * Bdim * 128) / 256, 256, 0, stream>>>(
      (const f16x4*)zh, (const f16x4*)fh, Pb, Qb);
  scanB_kernel<<<(Bdim * Hdim) / 256, 256, 0, stream>>>(Pb, Qb, hin,
                                                        out + (size_t)Mdim * Hdim);
  scanC_kernel<<<(NCHUNK * Bdim * 128) / 256, 256, 0, stream>>>(
      (const f16x4*)zh, (const f16x4*)fh, (const f16x4*)ogh, hin, (float4*)out);
}

// Round 12
// 318.267 us; speedup vs baseline: 1.2108x; 1.1929x over previous
//
#include <hip/hip_runtime.h>
#include <stdint.h>

#define Bdim 16
#define Sdim 4096
#define Hdim 512
#define Mdim (Bdim*Sdim)      // 65536
#define N3   (3*Hdim)         // 1536
#define Kdim 512
#define NCHUNK 64
#define CLEN  (Sdim/NCHUNK)   // 64

typedef __bf16 bf16;
typedef __bf16 bf16x4 __attribute__((ext_vector_type(4)));
typedef __bf16 bf16x8 __attribute__((ext_vector_type(8)));
typedef float  f32x4  __attribute__((ext_vector_type(4)));
typedef _Float16 f16;
typedef _Float16 f16x8 __attribute__((ext_vector_type(8)));

__device__ __forceinline__ void gload_lds16(const void* g, void* l) {
  __builtin_amdgcn_global_load_lds(
      (const __attribute__((address_space(1))) uint32_t*)g,
      (__attribute__((address_space(3))) uint32_t*)l, 16, 0, 0);
}

// ---------- fp32 -> bf16 convert, A and W fused in one dispatch ----------
__global__ void __launch_bounds__(256) cvt2_kernel(const float4* __restrict__ a,
                                                   bf16x4* __restrict__ oa, int nA,
                                                   const float4* __restrict__ w,
                                                   bf16x4* __restrict__ ow, int nW) {
  int i = blockIdx.x * blockDim.x + threadIdx.x;
  const float4* src; bf16x4* dst; int j;
  if (i < nA) { src = a; dst = oa; j = i; }
  else { j = i - nA; if (j >= nW) return; src = w; dst = ow; }
  float4 v = src[j];
  bf16x4 o;
  o.x = (bf16)v.x; o.y = (bf16)v.y; o.z = (bf16)v.z; o.w = (bf16)v.w;
  dst[j] = o;
}

// ================= 8-phase 256x256 MFMA GEMM (round-6 verbatim) ==========
#define BM 256
#define BN 256
#define BKT 64
#define NKT (Kdim/BKT)   // 8

__device__ __forceinline__ bf16x8 lds_ld(const char* p) { return *(const bf16x8*)p; }

__device__ __forceinline__ void read_af(bf16x8 (&d)[4][2], const char* Lb, uint32_t base,
                                        uint32_t swk0, uint32_t swk1, int mh) {
  #pragma unroll
  for (int i = 0; i < 4; ++i) {
    d[i][0] = lds_ld(Lb + base + mh * 8192 + i * 2048 + swk0);
    d[i][1] = lds_ld(Lb + base + mh * 8192 + i * 2048 + swk1);
  }
}
__device__ __forceinline__ void read_bf(bf16x8 (&d)[2][2], const char* Lb, uint32_t base,
                                        uint32_t swk0, uint32_t swk1, int nh) {
  #pragma unroll
  for (int j = 0; j < 2; ++j) {
    d[j][0] = lds_ld(Lb + base + nh * 4096 + j * 2048 + swk0);
    d[j][1] = lds_ld(Lb + base + nh * 4096 + j * 2048 + swk1);
  }
}
__device__ __forceinline__ void chunk16(f32x4 (&acc)[8][4], const bf16x8 (&a)[4][2],
                                        const bf16x8 (&b)[2][2], int mb, int nb) {
  __builtin_amdgcn_s_setprio(1);
  #pragma unroll
  for (int i = 0; i < 4; ++i)
    #pragma unroll
    for (int j = 0; j < 2; ++j)
      #pragma unroll
      for (int kk = 0; kk < 2; ++kk)
        acc[mb + i][nb + j] =
            __builtin_amdgcn_mfma_f32_16x16x32_bf16(a[i][kk], b[j][kk], acc[mb + i][nb + j], 0, 0, 0);
  __builtin_amdgcn_s_setprio(0);
}

template <int H>
__device__ __forceinline__ void stage_half(const bf16* Ag, const bf16* Bg, char* lds,
                                           uint32_t so0, uint32_t wbase) {
  if constexpr (H <= 4 * NKT - 1) {
    constexpr int th = H >> 2, ss = H & 3;
    constexpr uint32_t goff = (uint32_t)((ss >> 1) * 128 * Kdim + th * BKT);
    constexpr uint32_t lbase = (uint32_t)((th & 1) * 65536 + (ss & 1) * 32768 + (ss >> 1) * 16384);
    const bf16* gp = (ss & 1) ? Bg : Ag;
    gload_lds16(gp + goff + so0,         lds + lbase + wbase);
    gload_lds16(gp + goff + so0 + 32768, lds + lbase + 8192 + wbase);
  }
}

#define BAR()   __builtin_amdgcn_s_barrier()
#define LGKM0() do { asm volatile("s_waitcnt lgkmcnt(0)" ::: "memory"); \
                     __builtin_amdgcn_sched_barrier(0); } while (0)

template <int T>
__device__ __forceinline__ void ktile(char* lds, f32x4 (&acc)[8][4],
    bf16x8 (&af0)[4][2], bf16x8 (&af1)[4][2], bf16x8 (&bf0)[2][2], bf16x8 (&bf1)[2][2],
    const bf16* Ag, const bf16* Bg, uint32_t so0, uint32_t wbase,
    uint32_t aBase, uint32_t bBase, uint32_t swk0, uint32_t swk1) {
  const char* Lb = lds + (T & 1) * 65536;
  read_af(af0, Lb, aBase, swk0, swk1, 0);
  read_bf(bf0, Lb, bBase, swk0, swk1, 0);
  stage_half<4 * T + 6>(Ag, Bg, lds, so0, wbase);
  BAR(); LGKM0();
  chunk16(acc, af0, bf0, 0, 0);
  BAR();
  read_af(af1, Lb, aBase, swk0, swk1, 1);
  stage_half<4 * T + 7>(Ag, Bg, lds, so0, wbase);
  BAR(); LGKM0();
  chunk16(acc, af1, bf0, 4, 0);
  BAR();
  read_bf(bf1, Lb, bBase, swk0, swk1, 1);
  stage_half<4 * T + 8>(Ag, Bg, lds, so0, wbase);
  BAR(); LGKM0();
  chunk16(acc, af1, bf1, 4, 2);
  BAR();
  stage_half<4 * T + 9>(Ag, Bg, lds, so0, wbase);
  BAR(); LGKM0();
  chunk16(acc, af0, bf1, 0, 2);
  if constexpr (T <= NKT - 3) {
    asm volatile("s_waitcnt vmcnt(4)" ::: "memory");
  } else if constexpr (T == NKT - 2) {
    asm volatile("s_waitcnt vmcnt(0)" ::: "memory");
  }
  BAR();
}

__global__ void __launch_bounds__(512, 2) gemm_act_kernel(
    const bf16* __restrict__ A, const bf16* __restrict__ Wb,
    const float* __restrict__ bias,
    f16* __restrict__ zbuf, f16* __restrict__ fbuf, f16* __restrict__ ogbuf) {
  __shared__ char lds[131072];
  const int tid  = threadIdx.x;
  const int wid  = tid >> 6;
  const int lane = tid & 63;
  const int wr = wid >> 2, wc = wid & 3;
  const int bid = blockIdx.x;
  const int wg  = (bid & 7) * 192 + (bid >> 3);
  const int mt = wg / (N3 / BN);
  const int nt = wg % (N3 / BN);
  const int row0 = mt * BM;

  const bf16* Ag = A  + (size_t)row0 * Kdim;
  const bf16* Bg = Wb + (size_t)(nt * BN) * Kdim;

  const uint32_t r0   = tid >> 3;
  const uint32_t slot = tid & 7;
  const uint32_t so0  = r0 * Kdim + ((slot ^ (r0 & 7)) << 3);
  const uint32_t wbase = (uint32_t)(wid * 1024);
  const uint32_t kslot = lane >> 4;
  const uint32_t swk0 = ((kslot)     ^ (uint32_t)(lane & 7)) << 4;
  const uint32_t swk1 = ((4 + kslot) ^ (uint32_t)(lane & 7)) << 4;
  const uint32_t aBase = (uint32_t)((wr * 128 + (lane & 15)) * 128);
  const uint32_t bBase = (uint32_t)(32768 + (wc * 64 + (lane & 15)) * 128);

  f32x4 acc[8][4];
  #pragma unroll
  for (int m = 0; m < 8; ++m)
    #pragma unroll
    for (int n = 0; n < 4; ++n)
      acc[m][n] = (f32x4){0.f, 0.f, 0.f, 0.f};
  bf16x8 af0[4][2], af1[4][2], bf0[2][2], bf1[2][2];

  stage_half<0>(Ag, Bg, lds, so0, wbase);
  stage_half<1>(Ag, Bg, lds, so0, wbase);
  stage_half<2>(Ag, Bg, lds, so0, wbase);
  stage_half<3>(Ag, Bg, lds, so0, wbase);
  stage_half<4>(Ag, Bg, lds, so0, wbase);
  stage_half<5>(Ag, Bg, lds, so0, wbase);
  asm volatile("s_waitcnt vmcnt(4)" ::: "memory");
  BAR();

  ktile<0>(lds, acc, af0, af1, bf0, bf1, Ag, Bg, so0, wbase, aBase, bBase, swk0, swk1);
  ktile<1>(lds, acc, af0, af1, bf0, bf1, Ag, Bg, so0, wbase, aBase, bBase, swk0, swk1);
  ktile<2>(lds, acc, af0, af1, bf0, bf1, Ag, Bg, so0, wbase, aBase, bBase, swk0, swk1);
  ktile<3>(lds, acc, af0, af1, bf0, bf1, Ag, Bg, so0, wbase, aBase, bBase, swk0, swk1);
  ktile<4>(lds, acc, af0, af1, bf0, bf1, Ag, Bg, so0, wbase, aBase, bBase, swk0, swk1);
  ktile<5>(lds, acc, af0, af1, bf0, bf1, Ag, Bg, so0, wbase, aBase, bBase, swk0, swk1);
  ktile<6>(lds, acc, af0, af1, bf0, bf1, Ag, Bg, so0, wbase, aBase, bBase, swk0, swk1);
  ktile<7>(lds, acc, af0, af1, bf0, bf1, Ag, Bg, so0, wbase, aBase, bBase, swk0, swk1);

  __syncthreads();

  const int gate = nt >> 1;
  const int cb   = (nt & 1) * 256;
  f16* dst = (gate == 0) ? zbuf : ((gate == 1) ? fbuf : ogbuf);
  float bv[4];
  #pragma unroll
  for (int n = 0; n < 4; ++n)
    bv[n] = bias[gate * Hdim + cb + wc * 64 + n * 16 + (lane & 15)];

  #pragma unroll
  for (int m = 0; m < 8; ++m) {
    #pragma unroll
    for (int n = 0; n < 4; ++n) {
      int col = wc * 64 + n * 16 + (lane & 15);
      #pragma unroll
      for (int r = 0; r < 4; ++r) {
        int row = wr * 128 + m * 16 + (lane >> 4) * 4 + r;
        float y = acc[m][n][r] + bv[n];
        float v;
        if (gate == 0) {
          float e = __expf(2.f * y);
          v = 1.f - 2.f / (e + 1.f);
        } else {
          v = 1.f / (1.f + __expf(-y));
        }
        uint32_t byte = (uint32_t)(row * 512 + col * 2) ^ ((uint32_t)(row & 7) << 4);
        *(f16*)(lds + byte) = (f16)v;
      }
    }
  }
  __syncthreads();
  #pragma unroll
  for (int j = 0; j < 16; ++j) {
    int c = j * 512 + tid;
    int row = c >> 5, col8 = c & 31;
    uint32_t byte = (uint32_t)(row * 512 + col8 * 16) ^ ((uint32_t)(row & 7) << 4);
    f16x8 v = *(const f16x8*)(lds + byte);
    *(f16x8*)&dst[(size_t)(row0 + row) * Hdim + cb + col8 * 8] = v;
  }
}

// ---------- scan pass A: f16x8 loads, 8 channels/thread ----------
__global__ void __launch_bounds__(256) scanA_kernel(const f16x8* __restrict__ z8,
                                                    const f16x8* __restrict__ f8,
                                                    float* __restrict__ Pb,
                                                    float* __restrict__ Qb) {
  int u  = blockIdx.x * blockDim.x + threadIdx.x;  // 65536 = NCHUNK*B*64
  int ho = u & 63;
  int bc = u >> 6;
  int b  = bc & (Bdim - 1);
  int c  = bc >> 4;
  size_t base = ((size_t)(b * Sdim + c * CLEN)) * 64 + ho;  // in octs
  float P[8], Q[8];
  #pragma unroll
  for (int j = 0; j < 8; ++j) { P[j] = 1.f; Q[j] = 0.f; }
  #pragma unroll 4
  for (int s = 0; s < CLEN; ++s) {
    f16x8 fv = f8[base], zv = z8[base];
    #pragma unroll
    for (int j = 0; j < 8; ++j) {
      float f = (float)fv[j];
      Q[j] += f * ((float)zv[j] - Q[j]);
      P[j] *= (1.f - f);
    }
    base += 64;
  }
  int outi = ((c * Bdim + b) << 9) + ho * 8;
  *(float4*)&Pb[outi]     = make_float4(P[0], P[1], P[2], P[3]);
  *(float4*)&Pb[outi + 4] = make_float4(P[4], P[5], P[6], P[7]);
  *(float4*)&Qb[outi]     = make_float4(Q[0], Q[1], Q[2], Q[3]);
  *(float4*)&Qb[outi + 4] = make_float4(Q[4], Q[5], Q[6], Q[7]);
}

// ---------- scan pass B: scan chunk composites -> h_in per chunk + c_last ----------
__global__ void __launch_bounds__(256) scanB_kernel(const float* __restrict__ Pb,
                                                    const float* __restrict__ Qb,
                                                    float* __restrict__ hin,
                                                    float* __restrict__ c_last) {
  int t = blockIdx.x * blockDim.x + threadIdx.x;  // 8192 = B*H
  int h = t & (Hdim - 1), b = t >> 9;
  float hs = 0.f;
  #pragma unroll 8
  for (int c = 0; c < NCHUNK; ++c) {
    hin[c * (Bdim * Hdim) + t] = hs;
    int u = ((c * Bdim + b) << 9) + h;
    hs = Pb[u] * hs + Qb[u];
  }
  c_last[t] = hs;
}

// ---------- scan pass C: f16x8 loads, fuse out = og * h ----------
__global__ void __launch_bounds__(256) scanC_kernel(const f16x8* __restrict__ z8,
                                                    const f16x8* __restrict__ f8,
                                                    const f16x8* __restrict__ og8,
                                                    const float* __restrict__ hin,
                                                    float4* __restrict__ out4) {
  int u  = blockIdx.x * blockDim.x + threadIdx.x;  // 65536
  int ho = u & 63;
  int bc = u >> 6;
  int b  = bc & (Bdim - 1);
  int c  = bc >> 4;
  const float* hp = &hin[c * (Bdim * Hdim) + b * Hdim + ho * 8];
  float4 h0 = *(const float4*)hp;
  float4 h1 = *(const float4*)(hp + 4);
  float h[8] = {h0.x, h0.y, h0.z, h0.w, h1.x, h1.y, h1.z, h1.w};
  size_t brow = (size_t)(b * Sdim + c * CLEN);
  size_t base = brow * 64 + ho;       // gate octs
  size_t obase = brow * 128 + ho * 2; // out float4s
  #pragma unroll 4
  for (int s = 0; s < CLEN; ++s) {
    f16x8 fv = f8[base], zv = z8[base], ov = og8[base];
    #pragma unroll
    for (int j = 0; j < 8; ++j)
      h[j] += (float)fv[j] * ((float)zv[j] - h[j]);
    out4[obase]     = make_float4((float)ov[0] * h[0], (float)ov[1] * h[1],
                                  (float)ov[2] * h[2], (float)ov[3] * h[3]);
    out4[obase + 1] = make_float4((float)ov[4] * h[4], (float)ov[5] * h[5],
                                  (float)ov[6] * h[6], (float)ov[7] * h[7]);
    base += 64;
    obase += 128;
  }
}

extern "C" void kernel_launch(void* const* d_in, const int* in_sizes, int n_in,
                              void* d_out, int out_size, void* d_ws, size_t ws_size,
                              hipStream_t stream) {
  const float* inp  = (const float*)d_in[0];
  const float* W    = (const float*)d_in[1];
  const float* bias = (const float*)d_in[2];
  float* out = (float*)d_out;

  char* ws = (char*)d_ws;
  bf16* Abf = (bf16*)(ws);                   //  67,108,864
  bf16* Wbf = (bf16*)(ws + 67108864);        //   1,572,864
  f16*  zh  = (f16*) (ws + 68681728);        //  67,108,864
  f16*  fh  = (f16*) (ws + 135790592);       //  67,108,864
  f16*  ogh = (f16*) (ws + 202899456);       //  67,108,864
  float* Pb = (float*)(ws + 270008320);      //   2,097,152
  float* Qb = (float*)(ws + 272105472);      //   2,097,152
  float* hin= (float*)(ws + 274202624);      //   2,097,152

  // 1) convert A and W to bf16 in one dispatch
  {
    int nA = (Mdim * Kdim) / 4;  // 8,388,608
    int nW = (N3 * Kdim) / 4;    //   196,608
    cvt2_kernel<<<(nA + nW + 255) / 256, 256, 0, stream>>>(
        (const float4*)inp, (bf16x4*)Abf, nA, (const float4*)W, (bf16x4*)Wbf, nW);
  }
  // 2) GEMM + bias + activations -> fp16 gates (round-6 kernel, best measured)
  gemm_act_kernel<<<(Mdim / BM) * (N3 / BN), 512, 0, stream>>>(Abf, Wbf, bias,
                                                               zh, fh, ogh);
  // 3) chunked linear-recurrence scan (f16x8 vectorized)
  scanA_kernel<<<(NCHUNK * Bdim * 64) / 256, 256, 0, stream>>>(
      (const f16x8*)zh, (const f16x8*)fh, Pb, Qb);
  scanB_kernel<<<(Bdim * Hdim) / 256, 256, 0, stream>>>(Pb, Qb, hin,
                                                        out + (size_t)Mdim * Hdim);
  scanC_kernel<<<(NCHUNK * Bdim * 64) / 256, 256, 0, stream>>>(
      (const f16x8*)zh, (const f16x8*)fh, (const f16x8*)ogh, hin, (float4*)out);
}

// Round 13
// 307.151 us; speedup vs baseline: 1.2546x; 1.0362x over previous
//
#include <hip/hip_runtime.h>
#include <stdint.h>

#define Bdim 16
#define Sdim 4096
#define Hdim 512
#define Mdim (Bdim*Sdim)      // 65536
#define N3   (3*Hdim)        // 1536
#define Kdim 512
#define NCHUNK 128
#define CLEN  (Sdim/NCHUNK)   // 32

typedef __bf16 bf16;
typedef __bf16 bf16x4 __attribute__((ext_vector_type(4)));
typedef __bf16 bf16x8 __attribute__((ext_vector_type(8)));
typedef float  f32x4  __attribute__((ext_vector_type(4)));
typedef _Float16 f16;
typedef _Float16 f16x8 __attribute__((ext_vector_type(8)));

__device__ __forceinline__ void gload_lds16(const void* g, void* l) {
  __builtin_amdgcn_global_load_lds(
      (const __attribute__((address_space(1))) uint32_t*)g,
      (__attribute__((address_space(3))) uint32_t*)l, 16, 0, 0);
}

// ---------- fp32 -> bf16 convert, A and W fused in one dispatch ----------
__global__ void __launch_bounds__(256) cvt2_kernel(const float4* __restrict__ a,
                                                   bf16x4* __restrict__ oa, int nA,
                                                   const float4* __restrict__ w,
                                                   bf16x4* __restrict__ ow, int nW) {
  int i = blockIdx.x * blockDim.x + threadIdx.x;
  const float4* src; bf16x4* dst; int j;
  if (i < nA) { src = a; dst = oa; j = i; }
  else { j = i - nA; if (j >= nW) return; src = w; dst = ow; }
  float4 v = src[j];
  bf16x4 o;
  o.x = (bf16)v.x; o.y = (bf16)v.y; o.z = (bf16)v.z; o.w = (bf16)v.w;
  dst[j] = o;
}

// ================= 8-phase 256x256 MFMA GEMM (round-6 verbatim) ==========
#define BM 256
#define BN 256
#define BKT 64
#define NKT (Kdim/BKT)   // 8

__device__ __forceinline__ bf16x8 lds_ld(const char* p) { return *(const bf16x8*)p; }

__device__ __forceinline__ void read_af(bf16x8 (&d)[4][2], const char* Lb, uint32_t base,
                                        uint32_t swk0, uint32_t swk1, int mh) {
  #pragma unroll
  for (int i = 0; i < 4; ++i) {
    d[i][0] = lds_ld(Lb + base + mh * 8192 + i * 2048 + swk0);
    d[i][1] = lds_ld(Lb + base + mh * 8192 + i * 2048 + swk1);
  }
}
__device__ __forceinline__ void read_bf(bf16x8 (&d)[2][2], const char* Lb, uint32_t base,
                                        uint32_t swk0, uint32_t swk1, int nh) {
  #pragma unroll
  for (int j = 0; j < 2; ++j) {
    d[j][0] = lds_ld(Lb + base + nh * 4096 + j * 2048 + swk0);
    d[j][1] = lds_ld(Lb + base + nh * 4096 + j * 2048 + swk1);
  }
}
__device__ __forceinline__ void chunk16(f32x4 (&acc)[8][4], const bf16x8 (&a)[4][2],
                                        const bf16x8 (&b)[2][2], int mb, int nb) {
  __builtin_amdgcn_s_setprio(1);
  #pragma unroll
  for (int i = 0; i < 4; ++i)
    #pragma unroll
    for (int j = 0; j < 2; ++j)
      #pragma unroll
      for (int kk = 0; kk < 2; ++kk)
        acc[mb + i][nb + j] =
            __builtin_amdgcn_mfma_f32_16x16x32_bf16(a[i][kk], b[j][kk], acc[mb + i][nb + j], 0, 0, 0);
  __builtin_amdgcn_s_setprio(0);
}

template <int H>
__device__ __forceinline__ void stage_half(const bf16* Ag, const bf16* Bg, char* lds,
                                           uint32_t so0, uint32_t wbase) {
  if constexpr (H <= 4 * NKT - 1) {
    constexpr int th = H >> 2, ss = H & 3;
    constexpr uint32_t goff = (uint32_t)((ss >> 1) * 128 * Kdim + th * BKT);
    constexpr uint32_t lbase = (uint32_t)((th & 1) * 65536 + (ss & 1) * 32768 + (ss >> 1) * 16384);
    const bf16* gp = (ss & 1) ? Bg : Ag;
    gload_lds16(gp + goff + so0,         lds + lbase + wbase);
    gload_lds16(gp + goff + so0 + 32768, lds + lbase + 8192 + wbase);
  }
}

#define BAR()   __builtin_amdgcn_s_barrier()
#define LGKM0() do { asm volatile("s_waitcnt lgkmcnt(0)" ::: "memory"); \
                     __builtin_amdgcn_sched_barrier(0); } while (0)

template <int T>
__device__ __forceinline__ void ktile(char* lds, f32x4 (&acc)[8][4],
    bf16x8 (&af0)[4][2], bf16x8 (&af1)[4][2], bf16x8 (&bf0)[2][2], bf16x8 (&bf1)[2][2],
    const bf16* Ag, const bf16* Bg, uint32_t so0, uint32_t wbase,
    uint32_t aBase, uint32_t bBase, uint32_t swk0, uint32_t swk1) {
  const char* Lb = lds + (T & 1) * 65536;
  read_af(af0, Lb, aBase, swk0, swk1, 0);
  read_bf(bf0, Lb, bBase, swk0, swk1, 0);
  stage_half<4 * T + 6>(Ag, Bg, lds, so0, wbase);
  BAR(); LGKM0();
  chunk16(acc, af0, bf0, 0, 0);
  BAR();
  read_af(af1, Lb, aBase, swk0, swk1, 1);
  stage_half<4 * T + 7>(Ag, Bg, lds, so0, wbase);
  BAR(); LGKM0();
  chunk16(acc, af1, bf0, 4, 0);
  BAR();
  read_bf(bf1, Lb, bBase, swk0, swk1, 1);
  stage_half<4 * T + 8>(Ag, Bg, lds, so0, wbase);
  BAR(); LGKM0();
  chunk16(acc, af1, bf1, 4, 2);
  BAR();
  stage_half<4 * T + 9>(Ag, Bg, lds, so0, wbase);
  BAR(); LGKM0();
  chunk16(acc, af0, bf1, 0, 2);
  if constexpr (T <= NKT - 3) {
    asm volatile("s_waitcnt vmcnt(4)" ::: "memory");
  } else if constexpr (T == NKT - 2) {
    asm volatile("s_waitcnt vmcnt(0)" ::: "memory");
  }
  BAR();
}

__global__ void __launch_bounds__(512, 2) gemm_act_kernel(
    const bf16* __restrict__ A, const bf16* __restrict__ Wb,
    const float* __restrict__ bias,
    f16* __restrict__ zbuf, f16* __restrict__ fbuf, f16* __restrict__ ogbuf) {
  __shared__ char lds[131072];
  const int tid  = threadIdx.x;
  const int wid  = tid >> 6;
  const int lane = tid & 63;
  const int wr = wid >> 2, wc = wid & 3;
  const int bid = blockIdx.x;
  const int wg  = (bid & 7) * 192 + (bid >> 3);
  const int mt = wg / (N3 / BN);
  const int nt = wg % (N3 / BN);
  const int row0 = mt * BM;

  const bf16* Ag = A  + (size_t)row0 * Kdim;
  const bf16* Bg = Wb + (size_t)(nt * BN) * Kdim;

  const uint32_t r0   = tid >> 3;
  const uint32_t slot = tid & 7;
  const uint32_t so0  = r0 * Kdim + ((slot ^ (r0 & 7)) << 3);
  const uint32_t wbase = (uint32_t)(wid * 1024);
  const uint32_t kslot = lane >> 4;
  const uint32_t swk0 = ((kslot)     ^ (uint32_t)(lane & 7)) << 4;
  const uint32_t swk1 = ((4 + kslot) ^ (uint32_t)(lane & 7)) << 4;
  const uint32_t aBase = (uint32_t)((wr * 128 + (lane & 15)) * 128);
  const uint32_t bBase = (uint32_t)(32768 + (wc * 64 + (lane & 15)) * 128);

  f32x4 acc[8][4];
  #pragma unroll
  for (int m = 0; m < 8; ++m)
    #pragma unroll
    for (int n = 0; n < 4; ++n)
      acc[m][n] = (f32x4){0.f, 0.f, 0.f, 0.f};
  bf16x8 af0[4][2], af1[4][2], bf0[2][2], bf1[2][2];

  stage_half<0>(Ag, Bg, lds, so0, wbase);
  stage_half<1>(Ag, Bg, lds, so0, wbase);
  stage_half<2>(Ag, Bg, lds, so0, wbase);
  stage_half<3>(Ag, Bg, lds, so0, wbase);
  stage_half<4>(Ag, Bg, lds, so0, wbase);
  stage_half<5>(Ag, Bg, lds, so0, wbase);
  asm volatile("s_waitcnt vmcnt(4)" ::: "memory");
  BAR();

  ktile<0>(lds, acc, af0, af1, bf0, bf1, Ag, Bg, so0, wbase, aBase, bBase, swk0, swk1);
  ktile<1>(lds, acc, af0, af1, bf0, bf1, Ag, Bg, so0, wbase, aBase, bBase, swk0, swk1);
  ktile<2>(lds, acc, af0, af1, bf0, bf1, Ag, Bg, so0, wbase, aBase, bBase, swk0, swk1);
  ktile<3>(lds, acc, af0, af1, bf0, bf1, Ag, Bg, so0, wbase, aBase, bBase, swk0, swk1);
  ktile<4>(lds, acc, af0, af1, bf0, bf1, Ag, Bg, so0, wbase, aBase, bBase, swk0, swk1);
  ktile<5>(lds, acc, af0, af1, bf0, bf1, Ag, Bg, so0, wbase, aBase, bBase, swk0, swk1);
  ktile<6>(lds, acc, af0, af1, bf0, bf1, Ag, Bg, so0, wbase, aBase, bBase, swk0, swk1);
  ktile<7>(lds, acc, af0, af1, bf0, bf1, Ag, Bg, so0, wbase, aBase, bBase, swk0, swk1);

  __syncthreads();

  const int gate = nt >> 1;
  const int cb   = (nt & 1) * 256;
  f16* dst = (gate == 0) ? zbuf : ((gate == 1) ? fbuf : ogbuf);
  float bv[4];
  #pragma unroll
  for (int n = 0; n < 4; ++n)
    bv[n] = bias[gate * Hdim + cb + wc * 64 + n * 16 + (lane & 15)];

  #pragma unroll
  for (int m = 0; m < 8; ++m) {
    #pragma unroll
    for (int n = 0; n < 4; ++n) {
      int col = wc * 64 + n * 16 + (lane & 15);
      #pragma unroll
      for (int r = 0; r < 4; ++r) {
        int row = wr * 128 + m * 16 + (lane >> 4) * 4 + r;
        float y = acc[m][n][r] + bv[n];
        float v;
        if (gate == 0) {
          float e = __expf(2.f * y);
          v = 1.f - 2.f / (e + 1.f);
        } else {
          v = 1.f / (1.f + __expf(-y));
        }
        uint32_t byte = (uint32_t)(row * 512 + col * 2) ^ ((uint32_t)(row & 7) << 4);
        *(f16*)(lds + byte) = (f16)v;
      }
    }
  }
  __syncthreads();
  #pragma unroll
  for (int j = 0; j < 16; ++j) {
    int c = j * 512 + tid;
    int row = c >> 5, col8 = c & 31;
    uint32_t byte = (uint32_t)(row * 512 + col8 * 16) ^ ((uint32_t)(row & 7) << 4);
    f16x8 v = *(const f16x8*)(lds + byte);
    *(f16x8*)&dst[(size_t)(row0 + row) * Hdim + cb + col8 * 8] = v;
  }
}

// ---------- scan pass A: f16x8 loads, 8 ch/thread, NCHUNK=128 -> 8 waves/CU ----------
__global__ void __launch_bounds__(256) scanA_kernel(const f16x8* __restrict__ z8,
                                                    const f16x8* __restrict__ f8,
                                                    float* __restrict__ Pb,
                                                    float* __restrict__ Qb) {
  int u  = blockIdx.x * blockDim.x + threadIdx.x;  // 131072 = NCHUNK*B*64
  int ho = u & 63;
  int bc = u >> 6;
  int b  = bc & (Bdim - 1);
  int c  = bc >> 4;
  size_t base = ((size_t)(b * Sdim + c * CLEN)) * 64 + ho;  // in octs
  float P[8], Q[8];
  #pragma unroll
  for (int j = 0; j < 8; ++j) { P[j] = 1.f; Q[j] = 0.f; }
  #pragma unroll 4
  for (int s = 0; s < CLEN; ++s) {
    f16x8 fv = f8[base], zv = z8[base];
    #pragma unroll
    for (int j = 0; j < 8; ++j) {
      float f = (float)fv[j];
      Q[j] += f * ((float)zv[j] - Q[j]);
      P[j] *= (1.f - f);
    }
    base += 64;
  }
  int outi = ((c * Bdim + b) << 9) + ho * 8;
  *(float4*)&Pb[outi]     = make_float4(P[0], P[1], P[2], P[3]);
  *(float4*)&Pb[outi + 4] = make_float4(P[4], P[5], P[6], P[7]);
  *(float4*)&Qb[outi]     = make_float4(Q[0], Q[1], Q[2], Q[3]);
  *(float4*)&Qb[outi + 4] = make_float4(Q[4], Q[5], Q[6], Q[7]);
}

// ---------- scan pass B: scan chunk composites -> h_in per chunk + c_last ----------
__global__ void __launch_bounds__(256) scanB_kernel(const float* __restrict__ Pb,
                                                    const float* __restrict__ Qb,
                                                    float* __restrict__ hin,
                                                    float* __restrict__ c_last) {
  int t = blockIdx.x * blockDim.x + threadIdx.x;  // 8192 = B*H
  int h = t & (Hdim - 1), b = t >> 9;
  float hs = 0.f;
  #pragma unroll 8
  for (int c = 0; c < NCHUNK; ++c) {
    hin[c * (Bdim * Hdim) + t] = hs;
    int u = ((c * Bdim + b) << 9) + h;
    hs = Pb[u] * hs + Qb[u];
  }
  c_last[t] = hs;
}

// ---------- scan pass C: f16x8 loads, fuse out = og * h ----------
__global__ void __launch_bounds__(256) scanC_kernel(const f16x8* __restrict__ z8,
                                                    const f16x8* __restrict__ f8,
                                                    const f16x8* __restrict__ og8,
                                                    const float* __restrict__ hin,
                                                    float4* __restrict__ out4) {
  int u  = blockIdx.x * blockDim.x + threadIdx.x;  // 131072
  int ho = u & 63;
  int bc = u >> 6;
  int b  = bc & (Bdim - 1);
  int c  = bc >> 4;
  const float* hp = &hin[c * (Bdim * Hdim) + b * Hdim + ho * 8];
  float4 h0 = *(const float4*)hp;
  float4 h1 = *(const float4*)(hp + 4);
  float h[8] = {h0.x, h0.y, h0.z, h0.w, h1.x, h1.y, h1.z, h1.w};
  size_t brow = (size_t)(b * Sdim + c * CLEN);
  size_t base = brow * 64 + ho;       // gate octs
  size_t obase = brow * 128 + ho * 2; // out float4s
  #pragma unroll 4
  for (int s = 0; s < CLEN; ++s) {
    f16x8 fv = f8[base], zv = z8[base], ov = og8[base];
    #pragma unroll
    for (int j = 0; j < 8; ++j)
      h[j] += (float)fv[j] * ((float)zv[j] - h[j]);
    out4[obase]     = make_float4((float)ov[0] * h[0], (float)ov[1] * h[1],
                                  (float)ov[2] * h[2], (float)ov[3] * h[3]);
    out4[obase + 1] = make_float4((float)ov[4] * h[4], (float)ov[5] * h[5],
                                  (float)ov[6] * h[6], (float)ov[7] * h[7]);
    base += 64;
    obase += 128;
  }
}

extern "C" void kernel_launch(void* const* d_in, const int* in_sizes, int n_in,
                              void* d_out, int out_size, void* d_ws, size_t ws_size,
                              hipStream_t stream) {
  const float* inp  = (const float*)d_in[0];
  const float* W    = (const float*)d_in[1];
  const float* bias = (const float*)d_in[2];
  float* out = (float*)d_out;

  char* ws = (char*)d_ws;
  bf16* Abf = (bf16*)(ws);                   //  67,108,864
  bf16* Wbf = (bf16*)(ws + 67108864);        //   1,572,864
  f16*  zh  = (f16*) (ws + 68681728);        //  67,108,864
  f16*  fh  = (f16*) (ws + 135790592);       //  67,108,864
  f16*  ogh = (f16*) (ws + 202899456);       //  67,108,864
  float* Pb = (float*)(ws + 270008320);      //   4,194,304
  float* Qb = (float*)(ws + 274202624);      //   4,194,304
  float* hin= (float*)(ws + 278396928);      //   4,194,304  (peak ~282.6 MB)

  // 1) convert A and W to bf16 in one dispatch
  {
    int nA = (Mdim * Kdim) / 4;  // 8,388,608
    int nW = (N3 * Kdim) / 4;    //   196,608
    cvt2_kernel<<<(nA + nW + 255) / 256, 256, 0, stream>>>(
        (const float4*)inp, (bf16x4*)Abf, nA, (const float4*)W, (bf16x4*)Wbf, nW);
  }
  // 2) GEMM + bias + activations -> fp16 gates (round-6 kernel, best measured)
  gemm_act_kernel<<<(Mdim / BM) * (N3 / BN), 512, 0, stream>>>(Abf, Wbf, bias,
                                                               zh, fh, ogh);
  // 3) chunked linear-recurrence scan (f16x8 + full occupancy)
  scanA_kernel<<<(NCHUNK * Bdim * 64) / 256, 256, 0, stream>>>(
      (const f16x8*)zh, (const f16x8*)fh, Pb, Qb);
  scanB_kernel<<<(Bdim * Hdim) / 256, 256, 0, stream>>>(Pb, Qb, hin,
                                                        out + (size_t)Mdim * Hdim);
  scanC_kernel<<<(NCHUNK * Bdim * 64) / 256, 256, 0, stream>>>(
      (const f16x8*)zh, (const f16x8*)fh, (const f16x8*)ogh, hin, (float4*)out);
}

// Round 14
// 300.145 us; speedup vs baseline: 1.2839x; 1.0233x over previous
//
#include <hip/hip_runtime.h>
#include <stdint.h>

#define Bdim 16
#define Sdim 4096
#define Hdim 512
#define Mdim (Bdim*Sdim)      // 65536
#define N3   (3*Hdim)         // 1536
#define Kdim 512
#define NCHUNK 128
#define CLEN  (Sdim/NCHUNK)   // 32

typedef __bf16 bf16;
typedef __bf16 bf16x4 __attribute__((ext_vector_type(4)));
typedef __bf16 bf16x8 __attribute__((ext_vector_type(8)));
typedef float  f32x4  __attribute__((ext_vector_type(4)));
typedef _Float16 f16;
typedef _Float16 f16x8 __attribute__((ext_vector_type(8)));

__device__ __forceinline__ void gload_lds16(const void* g, void* l) {
  __builtin_amdgcn_global_load_lds(
      (const __attribute__((address_space(1))) uint32_t*)g,
      (__attribute__((address_space(3))) uint32_t*)l, 16, 0, 0);
}

// ---------- fp32 -> bf16 convert, A and W fused in one dispatch ----------
__global__ void __launch_bounds__(256) cvt2_kernel(const float4* __restrict__ a,
                                                   bf16x4* __restrict__ oa, int nA,
                                                   const float4* __restrict__ w,
                                                   bf16x4* __restrict__ ow, int nW) {
  int i = blockIdx.x * blockDim.x + threadIdx.x;
  const float4* src; bf16x4* dst; int j;
  if (i < nA) { src = a; dst = oa; j = i; }
  else { j = i - nA; if (j >= nW) return; src = w; dst = ow; }
  float4 v = src[j];
  bf16x4 o;
  o.x = (bf16)v.x; o.y = (bf16)v.y; o.z = (bf16)v.z; o.w = (bf16)v.w;
  dst[j] = o;
}

// ====== 128x256 MFMA GEMM, BK=32, 48KB LDS dbuf, acc[4][4] -> 2 blocks/CU ======
// A: (M,K) bf16 row-major; Wb: (N,K) bf16 row-major. C = A*Wb^T, fused act.
// Simple 2-phase loop (stage t+1 -> ds_read t -> MFMA -> __syncthreads);
// with 2 co-resident blocks/CU the other block's MFMA fills this block's
// barrier/stage drains (m114 cross-block overlap — the m97 mechanism).
// Swizzle: 16B slot s^((row>>1)&3) at stage source AND ds_read (0-conflict,
// verified r3-r13). Wave grid 2(M)x4(N), wave tile 64x64.
#define BM 128
#define BN 256
#define BK2 32
#define NT (Kdim/BK2)   // 16
#define LBUF 24576      // per-buffer: A 8KB @0, B 16KB @8192

__global__ void __launch_bounds__(512, 4) gemm_act_kernel(
    const bf16* __restrict__ A, const bf16* __restrict__ Wb,
    const float* __restrict__ bias,
    f16* __restrict__ zbuf, f16* __restrict__ fbuf, f16* __restrict__ ogbuf) {
  __shared__ char lds[2 * LBUF];   // 49152 B -> 2 blocks/CU
  const int tid  = threadIdx.x;
  const int wid  = tid >> 6;
  const int lane = tid & 63;
  const int wr = wid >> 2, wc = wid & 3;   // 2(M) x 4(N); wave tile 64x64
  // XCD-chunked bijective swizzle: 3072 blocks = 8 XCDs x 384
  const int bid = blockIdx.x;
  const int wg  = (bid & 7) * 384 + (bid >> 3);
  const int mt = wg / (N3 / BN);           // 512 M-tiles
  const int nt = wg % (N3 / BN);           // 6 N-tiles, inner -> A reuse per XCD
  const int row0 = mt * BM;

  const bf16* Ag = A  + (size_t)row0 * Kdim;
  const bf16* Bg = Wb + (size_t)(nt * BN) * Kdim;

  // staging: A = 128 rows x 4 slots x 16B = 8KB = 512 chunks (1/thread);
  //          B = 256 rows x 4 slots = 16KB = 1024 chunks (2/thread).
  // source slot pre-swizzled ^((row>>1)&3); LDS dest linear (chunk*16).
  uint32_t srcA;
  {
    int row = tid >> 2, slot = tid & 3;
    srcA = (uint32_t)(row * Kdim + ((slot ^ ((row >> 1) & 3)) << 3));
  }
  uint32_t srcB[2];
  #pragma unroll
  for (int i = 0; i < 2; ++i) {
    int c = i * 512 + tid;
    int row = c >> 2, slot = c & 3;
    srcB[i] = (uint32_t)(row * Kdim + ((slot ^ ((row >> 1) & 3)) << 3));
  }
  const uint32_t dstBase = (uint32_t)(wid * 1024);  // + lane*16 implicit

  // ds_read byte offsets within a buffer; row stride 64B, kslot = lane>>4
  uint32_t byteA[4], byteB[4];
  {
    int kslot = lane >> 4;
    #pragma unroll
    for (int m = 0; m < 4; ++m) {
      int row = wr * 64 + m * 16 + (lane & 15);
      byteA[m] = (uint32_t)(row * 64 + ((kslot ^ ((row >> 1) & 3)) << 4));
    }
    #pragma unroll
    for (int n = 0; n < 4; ++n) {
      int row = wc * 64 + n * 16 + (lane & 15);
      byteB[n] = (uint32_t)(8192 + row * 64 + ((kslot ^ ((row >> 1) & 3)) << 4));
    }
  }

  f32x4 acc[4][4];
  #pragma unroll
  for (int m = 0; m < 4; ++m)
    #pragma unroll
    for (int n = 0; n < 4; ++n)
      acc[m][n] = (f32x4){0.f, 0.f, 0.f, 0.f};

  // prologue: stage tile 0 into buf0
  {
    char* Ad = lds; char* Bd = lds + 8192;
    gload_lds16(Ag + srcA, Ad + dstBase);
    #pragma unroll
    for (int i = 0; i < 2; ++i) gload_lds16(Bg + srcB[i], Bd + i * 8192 + dstBase);
  }
  __syncthreads();

  for (int t = 0; t < NT; ++t) {
    if (t + 1 < NT) {  // stage next tile into other buffer
      char* Ad = lds + ((t + 1) & 1) * LBUF; char* Bd = Ad + 8192;
      gload_lds16(Ag + srcA + (t + 1) * BK2, Ad + dstBase);
      #pragma unroll
      for (int i = 0; i < 2; ++i)
        gload_lds16(Bg + srcB[i] + (t + 1) * BK2, Bd + i * 8192 + dstBase);
    }
    const char* Ab = lds + (t & 1) * LBUF;
    bf16x8 af[4], bfrag[4];
    #pragma unroll
    for (int m = 0; m < 4; ++m) af[m] = *(const bf16x8*)(Ab + byteA[m]);
    #pragma unroll
    for (int n = 0; n < 4; ++n) bfrag[n] = *(const bf16x8*)(Ab + byteB[n]);
    #pragma unroll
    for (int m = 0; m < 4; ++m)
      #pragma unroll
      for (int n = 0; n < 4; ++n)
        acc[m][n] = __builtin_amdgcn_mfma_f32_16x16x32_bf16(af[m], bfrag[n], acc[m][n], 0, 0, 0);
    __syncthreads();  // drain hidden by the co-resident block's compute
  }

  // ---- epilogue: activation, repack via LDS (32KB), coalesced f16x8 stores ----
  const int gate = nt >> 1;                 // BN=256 divides each 512-col gate
  const int cbn  = (nt & 1) * 256;
  f16* dst = (gate == 0) ? zbuf : ((gate == 1) ? fbuf : ogbuf);
  float bv[4];
  #pragma unroll
  for (int n = 0; n < 4; ++n)
    bv[n] = bias[gate * Hdim + cbn + wc * 64 + n * 16 + (lane & 15)];

  #pragma unroll
  for (int R = 0; R < 2; ++R) {
    // write: waves with wr==R scatter their 64x64 tile (rows R*64..R*64+63)
    if (wr == R) {
      #pragma unroll
      for (int m = 0; m < 4; ++m) {
        #pragma unroll
        for (int n = 0; n < 4; ++n) {
          int col = wc * 64 + n * 16 + (lane & 15);
          #pragma unroll
          for (int r = 0; r < 4; ++r) {
            int Lrow = m * 16 + (lane >> 4) * 4 + r;   // 0..63
            float y = acc[m][n][r] + bv[n];
            float v;
            if (gate == 0) {                       // tanh(y) = 1 - 2/(e^{2y}+1)
              float e = __expf(2.f * y);
              v = 1.f - 2.f / (e + 1.f);
            } else {                               // sigmoid
              v = 1.f / (1.f + __expf(-y));
            }
            uint32_t byte = (uint32_t)(Lrow * 512 + col * 2) ^ ((uint32_t)(Lrow & 7) << 4);
            *(f16*)(lds + byte) = (f16)v;
          }
        }
      }
    }
    __syncthreads();
    // read + coalesced stores: 4 rounds x 512 threads x 16B = 32KB
    #pragma unroll
    for (int j = 0; j < 4; ++j) {
      int c = j * 512 + tid;
      int Lrow = c >> 5, col8 = c & 31;
      uint32_t byte = (uint32_t)(Lrow * 512 + col8 * 16) ^ ((uint32_t)(Lrow & 7) << 4);
      f16x8 v = *(const f16x8*)(lds + byte);
      *(f16x8*)&dst[(size_t)(row0 + R * 64 + Lrow) * Hdim + cbn + col8 * 8] = v;
    }
    __syncthreads();  // reads retired before next round's writes
  }
}

// ---------- scan pass A: f16x8 loads, 8 ch/thread, NCHUNK=128 -> 8 waves/CU ----------
__global__ void __launch_bounds__(256) scanA_kernel(const f16x8* __restrict__ z8,
                                                    const f16x8* __restrict__ f8,
                                                    float* __restrict__ Pb,
                                                    float* __restrict__ Qb) {
  int u  = blockIdx.x * blockDim.x + threadIdx.x;  // 131072 = NCHUNK*B*64
  int ho = u & 63;
  int bc = u >> 6;
  int b  = bc & (Bdim - 1);
  int c  = bc >> 4;
  size_t base = ((size_t)(b * Sdim + c * CLEN)) * 64 + ho;  // in octs
  float P[8], Q[8];
  #pragma unroll
  for (int j = 0; j < 8; ++j) { P[j] = 1.f; Q[j] = 0.f; }
  #pragma unroll 4
  for (int s = 0; s < CLEN; ++s) {
    f16x8 fv = f8[base], zv = z8[base];
    #pragma unroll
    for (int j = 0; j < 8; ++j) {
      float f = (float)fv[j];
      Q[j] += f * ((float)zv[j] - Q[j]);
      P[j] *= (1.f - f);
    }
    base += 64;
  }
  int outi = ((c * Bdim + b) << 9) + ho * 8;
  *(float4*)&Pb[outi]     = make_float4(P[0], P[1], P[2], P[3]);
  *(float4*)&Pb[outi + 4] = make_float4(P[4], P[5], P[6], P[7]);
  *(float4*)&Qb[outi]     = make_float4(Q[0], Q[1], Q[2], Q[3]);
  *(float4*)&Qb[outi + 4] = make_float4(Q[4], Q[5], Q[6], Q[7]);
}

// ---------- scan pass B: scan chunk composites -> h_in per chunk + c_last ----------
__global__ void __launch_bounds__(256) scanB_kernel(const float* __restrict__ Pb,
                                                    const float* __restrict__ Qb,
                                                    float* __restrict__ hin,
                                                    float* __restrict__ c_last) {
  int t = blockIdx.x * blockDim.x + threadIdx.x;  // 8192 = B*H
  int h = t & (Hdim - 1), b = t >> 9;
  float hs = 0.f;
  #pragma unroll 8
  for (int c = 0; c < NCHUNK; ++c) {
    hin[c * (Bdim * Hdim) + t] = hs;
    int u = ((c * Bdim + b) << 9) + h;
    hs = Pb[u] * hs + Qb[u];
  }
  c_last[t] = hs;
}

// ---------- scan pass C: f16x8 loads, fuse out = og * h ----------
__global__ void __launch_bounds__(256) scanC_kernel(const f16x8* __restrict__ z8,
                                                    const f16x8* __restrict__ f8,
                                                    const f16x8* __restrict__ og8,
                                                    const float* __restrict__ hin,
                                                    float4* __restrict__ out4) {
  int u  = blockIdx.x * blockDim.x + threadIdx.x;  // 131072
  int ho = u & 63;
  int bc = u >> 6;
  int b  = bc & (Bdim - 1);
  int c  = bc >> 4;
  const float* hp = &hin[c * (Bdim * Hdim) + b * Hdim + ho * 8];
  float4 h0 = *(const float4*)hp;
  float4 h1 = *(const float4*)(hp + 4);
  float h[8] = {h0.x, h0.y, h0.z, h0.w, h1.x, h1.y, h1.z, h1.w};
  size_t brow = (size_t)(b * Sdim + c * CLEN);
  size_t base = brow * 64 + ho;       // gate octs
  size_t obase = brow * 128 + ho * 2; // out float4s
  #pragma unroll 4
  for (int s = 0; s < CLEN; ++s) {
    f16x8 fv = f8[base], zv = z8[base], ov = og8[base];
    #pragma unroll
    for (int j = 0; j < 8; ++j)
      h[j] += (float)fv[j] * ((float)zv[j] - h[j]);
    out4[obase]     = make_float4((float)ov[0] * h[0], (float)ov[1] * h[1],
                                  (float)ov[2] * h[2], (float)ov[3] * h[3]);
    out4[obase + 1] = make_float4((float)ov[4] * h[4], (float)ov[5] * h[5],
                                  (float)ov[6] * h[6], (float)ov[7] * h[7]);
    base += 64;
    obase += 128;
  }
}

extern "C" void kernel_launch(void* const* d_in, const int* in_sizes, int n_in,
                              void* d_out, int out_size, void* d_ws, size_t ws_size,
                              hipStream_t stream) {
  const float* inp  = (const float*)d_in[0];
  const float* W    = (const float*)d_in[1];
  const float* bias = (const float*)d_in[2];
  float* out = (float*)d_out;

  char* ws = (char*)d_ws;
  bf16* Abf = (bf16*)(ws);                   //  67,108,864
  bf16* Wbf = (bf16*)(ws + 67108864);        //   1,572,864
  f16*  zh  = (f16*) (ws + 68681728);        //  67,108,864
  f16*  fh  = (f16*) (ws + 135790592);       //  67,108,864
  f16*  ogh = (f16*) (ws + 202899456);       //  67,108,864
  float* Pb = (float*)(ws + 270008320);      //   4,194,304
  float* Qb = (float*)(ws + 274202624);      //   4,194,304
  float* hin= (float*)(ws + 278396928);      //   4,194,304  (peak ~282.6 MB)

  // 1) convert A and W to bf16 in one dispatch
  {
    int nA = (Mdim * Kdim) / 4;  // 8,388,608
    int nW = (N3 * Kdim) / 4;    //   196,608
    cvt2_kernel<<<(nA + nW + 255) / 256, 256, 0, stream>>>(
        (const float4*)inp, (bf16x4*)Abf, nA, (const float4*)W, (bf16x4*)Wbf, nW);
  }
  // 2) GEMM + bias + activations -> fp16 gates (128x256, 2 blocks/CU)
  gemm_act_kernel<<<(Mdim / BM) * (N3 / BN), 512, 0, stream>>>(Abf, Wbf, bias,
                                                               zh, fh, ogh);
  // 3) chunked linear-recurrence scan (f16x8 + full occupancy)
  scanA_kernel<<<(NCHUNK * Bdim * 64) / 256, 256, 0, stream>>>(
      (const f16x8*)zh, (const f16x8*)fh, Pb, Qb);
  scanB_kernel<<<(Bdim * Hdim) / 256, 256, 0, stream>>>(Pb, Qb, hin,
                                                        out + (size_t)Mdim * Hdim);
  scanC_kernel<<<(NCHUNK * Bdim * 64) / 256, 256, 0, stream>>>(
      (const f16x8*)zh, (const f16x8*)fh, (const f16x8*)ogh, hin, (float4*)out);
}